// Round 9
// baseline (179.615 us; speedup 1.0000x reference)
//
#include <hip/hip_runtime.h>
#include <stdint.h>

typedef float f32x4 __attribute__((ext_vector_type(4)));
typedef int   i32x4 __attribute__((ext_vector_type(4)));
typedef __bf16 bf16x8 __attribute__((ext_vector_type(8)));

#define NN 8192
#define DDIM 128
#define RSTRIDE 72      // LDS tile row: 32 bf16 (64 B) + 8 B pad (18-word stride)
#define TILE_B 9216     // 128 rows * 72 B
#define BUF_B  36864    // 4 tiles (AH, AL, BH, BL)

// byte offsets within a buffer
#define OFF_AH 0
#define OFF_AL 9216
#define OFF_BH 18432
#define OFF_BL 27648
// aux after the two buffers
#define OFF_ILS 73728
#define OFF_N1  74240
#define OFF_N2  74752
#define LDS_TOT 75264

__device__ __forceinline__ uint32_t pk2(__bf16 a, __bf16 b) {
    return (uint32_t)__builtin_bit_cast(unsigned short, a)
         | ((uint32_t)__builtin_bit_cast(unsigned short, b) << 16);
}

// RNE hi/lo split of 4 scaled f32 (verified R3/R5/R6/R7)
__device__ __forceinline__ void split4(f32x4 x, uint2& hi, uint2& lo) {
    __bf16 h0 = (__bf16)x[0], h1 = (__bf16)x[1], h2 = (__bf16)x[2], h3 = (__bf16)x[3];
    hi.x = pk2(h0, h1); hi.y = pk2(h2, h3);
    __bf16 l0 = (__bf16)(x[0] - (float)h0);
    __bf16 l1 = (__bf16)(x[1] - (float)h1);
    __bf16 l2 = (__bf16)(x[2] - (float)h2);
    __bf16 l3 = (__bf16)(x[3] - (float)h3);
    lo.x = pk2(l0, l1); lo.y = pk2(l2, l3);
}

// LDS-visibility-only barrier: does NOT drain vmcnt (verified R7).
__device__ __forceinline__ void lds_barrier() {
    asm volatile("s_waitcnt lgkmcnt(0)" ::: "memory");
    __builtin_amdgcn_sched_barrier(0);
    __builtin_amdgcn_s_barrier();
    __builtin_amdgcn_sched_barrier(0);
}

// Fused TGP: split-once-to-LDS bf16 3-term GEMM + in-LDS norms + fused epilogue.
// 128x128 tile, 256 thr (2x2 waves of 64x64), BK=32, DOUBLE-buffered split
// tiles, ONE lds_barrier per chunk; global prefetch 2 chunks deep stays in
// flight across barriers. Buffer b holds chunks with (chunk & 1) == b; reads
// of buffer X finish one barrier before X is overwritten.
__global__ __launch_bounds__(256, 2) void tgp_kernel(
    const float* __restrict__ X1, const float* __restrict__ X2,
    const float* __restrict__ log_l,
    const float* __restrict__ log_theta_l, const float* __restrict__ bparam,
    const int* __restrict__ task1, const int* __restrict__ task2,
    float* __restrict__ C)
{
    __shared__ __align__(16) char smem[LDS_TOT];
    float* const ils = (float*)(smem + OFF_ILS);
    float* const n1s = (float*)(smem + OFF_N1);
    float* const n2s = (float*)(smem + OFF_N2);

    const int t = threadIdx.x;
    const int lane = t & 63;
    const int wv = t >> 6;
    const int wr = wv >> 1, wc = wv & 1;
    const int lr = lane & 15, lg = lane >> 4;
    const int kq = t & 7;     // 8-B col unit within 32-col chunk
    const int rg = t >> 3;    // 0..31 row within each 32-row stripe

    // L2 super-tile ordering (verified R7)
    int wg = blockIdx.x;
    int xcd = wg & 7;
    int r = wg >> 3;
    int su = r >> 6;
    int inner = r & 63;
    int tm = xcd * 8 + (inner >> 3);
    int tn = su * 8 + (inner & 7);

    const float* Ag = X1 + (size_t)tm * 128 * DDIM;
    const float* Bg = X2 + (size_t)tn * 128 * DDIM;

    f32x4 aV[4], bV[4];
    #define LOADC(c) do {                                                        \
        _Pragma("unroll")                                                        \
        for (int e = 0; e < 4; ++e) {                                            \
            aV[e] = *(const f32x4*)(Ag + (size_t)(e * 32 + rg) * DDIM + (c) * 32 + kq * 4); \
            bV[e] = *(const f32x4*)(Bg + (size_t)(e * 32 + rg) * DDIM + (c) * 32 + kq * 4); \
        }                                                                        \
    } while (0)

    float nA[4] = {0.f, 0.f, 0.f, 0.f};
    float nB[4] = {0.f, 0.f, 0.f, 0.f};

    #define SPLITW(c, bb) do {                                                   \
        f32x4 il4 = *(const f32x4*)(ils + (c) * 32 + kq * 4);                    \
        char* base = smem + (bb) * BUF_B;                                        \
        _Pragma("unroll")                                                        \
        for (int e = 0; e < 4; ++e) {                                            \
            int row = e * 32 + rg;                                               \
            f32x4 xa = aV[e] * il4;                                              \
            f32x4 xb = bV[e] * il4;                                              \
            nA[e] += xa[0]*xa[0] + xa[1]*xa[1] + xa[2]*xa[2] + xa[3]*xa[3];      \
            nB[e] += xb[0]*xb[0] + xb[1]*xb[1] + xb[2]*xb[2] + xb[3]*xb[3];      \
            uint2 hA, lA, hB, lB;                                                \
            split4(xa, hA, lA);                                                  \
            split4(xb, hB, lB);                                                  \
            int boff = row * RSTRIDE + kq * 8;                                   \
            *(uint2*)(base + OFF_AH + boff) = hA;                                \
            *(uint2*)(base + OFF_AL + boff) = lA;                                \
            *(uint2*)(base + OFF_BH + boff) = hB;                                \
            *(uint2*)(base + OFF_BL + boff) = lB;                                \
        }                                                                        \
    } while (0)

    f32x4 acc[4][4];
    #pragma unroll
    for (int i = 0; i < 4; ++i)
        #pragma unroll
        for (int j = 0; j < 4; ++j) acc[i][j] = (f32x4){0.f, 0.f, 0.f, 0.f};

    #define FRAGMM(bb) do {                                                      \
        const char* base = smem + (bb) * BUF_B;                                  \
        bf16x8 ah[4], bh[4], xf[4];                                              \
        __builtin_amdgcn_s_setprio(1);                                           \
        _Pragma("unroll")                                                        \
        for (int mi = 0; mi < 4; ++mi) {                                         \
            int off = (wr * 64 + mi * 16 + lr) * RSTRIDE + lg * 16;              \
            ah[mi] = *(const bf16x8*)(base + OFF_AH + off);                      \
        }                                                                        \
        _Pragma("unroll")                                                        \
        for (int ni = 0; ni < 4; ++ni) {                                         \
            int off = (wc * 64 + ni * 16 + lr) * RSTRIDE + lg * 16;              \
            bh[ni] = *(const bf16x8*)(base + OFF_BH + off);                      \
        }                                                                        \
        _Pragma("unroll")                                                        \
        for (int mi = 0; mi < 4; ++mi)                                           \
            _Pragma("unroll")                                                    \
            for (int ni = 0; ni < 4; ++ni)                                       \
                acc[mi][ni] = __builtin_amdgcn_mfma_f32_16x16x32_bf16(bh[ni], ah[mi], acc[mi][ni], 0, 0, 0); \
        _Pragma("unroll")                                                        \
        for (int mi = 0; mi < 4; ++mi) {                                         \
            int off = (wr * 64 + mi * 16 + lr) * RSTRIDE + lg * 16;              \
            xf[mi] = *(const bf16x8*)(base + OFF_AL + off);                      \
        }                                                                        \
        _Pragma("unroll")                                                        \
        for (int mi = 0; mi < 4; ++mi)                                           \
            _Pragma("unroll")                                                    \
            for (int ni = 0; ni < 4; ++ni)                                       \
                acc[mi][ni] = __builtin_amdgcn_mfma_f32_16x16x32_bf16(bh[ni], xf[mi], acc[mi][ni], 0, 0, 0); \
        _Pragma("unroll")                                                        \
        for (int ni = 0; ni < 4; ++ni) {                                         \
            int off = (wc * 64 + ni * 16 + lr) * RSTRIDE + lg * 16;              \
            xf[ni] = *(const bf16x8*)(base + OFF_BL + off);                      \
        }                                                                        \
        _Pragma("unroll")                                                        \
        for (int mi = 0; mi < 4; ++mi)                                           \
            _Pragma("unroll")                                                    \
            for (int ni = 0; ni < 4; ++ni)                                       \
                acc[mi][ni] = __builtin_amdgcn_mfma_f32_16x16x32_bf16(xf[ni], ah[mi], acc[mi][ni], 0, 0, 0); \
        __builtin_amdgcn_s_setprio(0);                                           \
    } while (0)

    // ---- prologue ----
    LOADC(0);
    if (t < 128) ils[t] = __expf(-log_l[t]);
    __syncthreads();           // ils visible
    SPLITW(0, 0);
    LOADC(1);
    lds_barrier();             // buf0 (chunk 0) visible

    // ---- main: 1 barrier per chunk; compiler interleaves within segments ----
    FRAGMM(0); SPLITW(1, 1); LOADC(2); lds_barrier();
    FRAGMM(1); SPLITW(2, 0); LOADC(3); lds_barrier();
    FRAGMM(0); SPLITW(3, 1);           lds_barrier();
    FRAGMM(1);

    #undef LOADC
    #undef SPLITW
    #undef FRAGMM

    // ---- norm reduce: 8-lane groups over kq; lane kq==0 owns row rg ----
    #pragma unroll
    for (int e = 0; e < 4; ++e) {
        #pragma unroll
        for (int off = 1; off < 8; off <<= 1) {
            nA[e] += __shfl_xor(nA[e], off);
            nB[e] += __shfl_xor(nB[e], off);
        }
    }
    if (kq == 0) {
        #pragma unroll
        for (int e = 0; e < 4; ++e) {
            n1s[e * 32 + rg] = nA[e];
            n2s[e * 32 + rg] = nB[e];
        }
    }
    __syncthreads();           // norms visible

    // ---- epilogue (verified mapping): lane lr = A-row slice,
    //      reg r = 4 consecutive cols at lg*4 (swapped operands) ----
    float logt = log_theta_l[0];
    float bb = bparam[0];
    float lam = fminf(fmaxf(2.f / (1.f + __expf(bb)) - 1.f, 0.f), 1.f);
    int rbase = tm * 128, cbase = tn * 128;

    #pragma unroll
    for (int mi = 0; mi < 4; ++mi) {
        int rowl = wr * 64 + mi * 16 + lr;
        float n1v = n1s[rowl];
        int t1v = task1[rbase + rowl];
        #pragma unroll
        for (int ni = 0; ni < 4; ++ni) {
            int coll = wc * 64 + ni * 16 + lg * 4;
            f32x4 n2v = *(const f32x4*)(n2s + coll);
            i32x4 t2v = *(const i32x4*)(task2 + cbase + coll);
            f32x4 kv;
            #pragma unroll
            for (int rix = 0; rix < 4; ++rix) {
                float s = fmaxf(n1v + n2v[rix] - 2.f * acc[mi][ni][rix], 0.f);
                float k = __expf(fmaf(-0.5f, s, logt));
                kv[rix] = (t1v != t2v[rix]) ? k * lam : k;
            }
            *(f32x4*)(C + (size_t)(rbase + rowl) * NN + cbase + coll) = kv;
        }
    }
}

extern "C" void kernel_launch(void* const* d_in, const int* in_sizes, int n_in,
                              void* d_out, int out_size, void* d_ws, size_t ws_size,
                              hipStream_t stream)
{
    const float* X1 = (const float*)d_in[0];
    const float* X2 = (const float*)d_in[1];
    const float* log_l = (const float*)d_in[2];
    const float* log_theta = (const float*)d_in[3];
    const float* bp = (const float*)d_in[4];
    const int* t1 = (const int*)d_in[5];
    const int* t2 = (const int*)d_in[6];
    float* C = (float*)d_out;
    (void)d_ws; (void)ws_size; (void)in_sizes; (void)n_in; (void)out_size;

    tgp_kernel<<<4096, 256, 0, stream>>>(X1, X2, log_l, log_theta, bp, t1, t2, C);
}